// Round 6
// baseline (899.335 us; speedup 1.0000x reference)
//
#include <hip/hip_runtime.h>

// PairwiseMLPLinkPredictor on MI355X (gfx950)
// feats = bf16(x[u]) * bf16(x[v]);  h1 = relu(feats@W1+b1);  h2 = relu(h1@W2+b2);
// out = h2@W3 + b3.
//
// R5: occupancy fix. Unified-reg-file model (fits R1/R2/R4b data): arch VGPR +
// AGPR <= 64/wave needed for 2 x 16-wave blocks/CU. So: no weight-frag register
// preloads (per-kt B loads from L2), acc kept at 16+8 regs, single 32 KB LDS
// buffer (feats dead after GEMM1; h1 dead after GEMM2; one extra barrier).
// Keep R4b's register-staged pipelined gather + atomic layer-3.

typedef __attribute__((ext_vector_type(8))) short short8;   // 8 bf16 = 4 VGPRs
typedef __attribute__((ext_vector_type(4))) float floatx4;  // MFMA C/D frag
typedef __attribute__((ext_vector_type(4))) unsigned uintx4;
typedef __attribute__((ext_vector_type(2))) int intx2;

#define MT 64         // pairs per tile
#define NTHREADS 1024 // 16 waves
#define NBLOCKS 512   // 2 blocks/CU resident

__device__ __forceinline__ unsigned short f2bf(float f) {
  union { float f; unsigned u; } a; a.f = f;
  unsigned r = a.u + 0x7FFFu + ((a.u >> 16) & 1u);   // RNE
  return (unsigned short)(r >> 16);
}

// packed bf16 x2 multiply via f32 (unpack, mul, RNE repack)
__device__ __forceinline__ unsigned bf16mul2(unsigned ua, unsigned ub) {
  float lo = __uint_as_float(ua << 16)          * __uint_as_float(ub << 16);
  float hi = __uint_as_float(ua & 0xFFFF0000u) * __uint_as_float(ub & 0xFFFF0000u);
  return (unsigned)f2bf(lo) | ((unsigned)f2bf(hi) << 16);
}

// ---------- prologue: x -> bf16 table ----------
__global__ void cast_x_kernel(const float* __restrict__ x, unsigned short* __restrict__ xb, int n4) {
  int i = blockIdx.x * blockDim.x + threadIdx.x;
  if (i >= n4) return;
  float4 v = ((const float4*)x)[i];
  ushort4 o;
  o.x = f2bf(v.x); o.y = f2bf(v.y); o.z = f2bf(v.z); o.w = f2bf(v.w);
  ((ushort4*)xb)[i] = o;
}

// ---------- prologue: W1 [256,256] / W2 [256,128] -> bf16, transposed to [n][k] ----------
__global__ void prep_w_kernel(const float* __restrict__ W1, const float* __restrict__ W2,
                              unsigned short* __restrict__ w1t, unsigned short* __restrict__ w2t) {
  int i = blockIdx.x * blockDim.x + threadIdx.x;
  if (i < 256 * 256) {
    int k = i >> 8, n = i & 255;
    w1t[n * 256 + k] = f2bf(W1[k * 256 + n]);
  } else {
    int j = i - 256 * 256;
    if (j < 128 * 256) {
      int k = j >> 7, n = j & 127;
      w2t[n * 256 + k] = f2bf(W2[k * 128 + n]);
    }
  }
}

// ---------- out[i] = b3 (scores accumulate via atomics) ----------
__global__ void init_out_kernel(float* __restrict__ out, const float* __restrict__ b3, int E) {
  int i = blockIdx.x * blockDim.x + threadIdx.x;
  if (i < E) out[i] = b3[0];
}

// ---------- fused pairwise MLP, persistent + pipelined, single LDS buffer ----------
__global__ __launch_bounds__(NTHREADS, 8) void mlp_kernel(
    const unsigned short* __restrict__ xb,
    const unsigned short* __restrict__ w1t,
    const unsigned short* __restrict__ w2t,
    const float* __restrict__ b1,
    const float* __restrict__ b2,
    const float* __restrict__ w3,
    const int* __restrict__ ep,
    float* __restrict__ out,
    int E)
{
  // 64 rows x 256 bf16 = 32768 B. 16B chunks XOR-swizzled by (row & 15):
  // conflict-free stride-512 ds_read_b128 without padding.
  __shared__ __align__(16) unsigned short buf[MT * 256];
  char* const ldsb = (char*)buf;

  const int tid  = threadIdx.x;
  const int wv   = tid >> 6;      // 0..15
  const int lane = tid & 63;
  const int q    = lane >> 4;     // quad 0..3
  const int r16  = lane & 15;
  const int c    = tid & 31;      // 16B chunk within 512B row (staging)
  const int mr0  = tid >> 5;      // staging rows mr0, mr0+32

  const int ntiles = (E + MT - 1) / MT;

  // ---- prologue: stage tile t0 ----
  {
    int t0 = blockIdx.x;
    #pragma unroll
    for (int s = 0; s < 2; ++s) {
      int m = mr0 + 32 * s;
      int g = t0 * MT + m; if (g >= E) g = E - 1;
      intx2 uv = __builtin_nontemporal_load((const intx2*)(ep + 2 * (size_t)g));
      uintx4 a = __builtin_nontemporal_load((const uintx4*)(xb + ((size_t)uv.x << 8) + (c << 3)));
      uintx4 b = __builtin_nontemporal_load((const uintx4*)(xb + ((size_t)uv.y << 8) + (c << 3)));
      uintx4 pv;
      #pragma unroll
      for (int tt = 0; tt < 4; ++tt) pv[tt] = bf16mul2(a[tt], b[tt]);
      *(uintx4*)(ldsb + m * 512 + ((c ^ (m & 15)) << 4)) = pv;
    }
  }
  __syncthreads();

  for (int t = blockIdx.x; t < ntiles; t += NBLOCKS) {
    const int tn = (t + NBLOCKS < ntiles) ? (t + NBLOCKS) : t;

    // ---- (1) prefetch ep indices for next tile ----
    intx2 uvn[2];
    #pragma unroll
    for (int s = 0; s < 2; ++s) {
      int g = tn * MT + mr0 + 32 * s; if (g >= E) g = E - 1;
      uvn[s] = __builtin_nontemporal_load((const intx2*)(ep + 2 * (size_t)g));
    }

    // ---- (2) GEMM1: wave owns 64 rows x 16 cols (n = wv*16 + r16) ----
    const unsigned short* const b1p = w1t + (wv * 16 + r16) * 256 + q * 8;
    floatx4 acc[4];
    #pragma unroll
    for (int i = 0; i < 4; ++i) acc[i] = (floatx4){0.f, 0.f, 0.f, 0.f};

    char* const a1base = ldsb + r16 * 512;
    #pragma unroll
    for (int kt = 0; kt < 8; ++kt) {
      const int aoff = (kt << 6) ^ ((q ^ r16) << 4);
      short8 bv1 = *(const short8*)(b1p + kt * 32);
      short8 av[4];
      #pragma unroll
      for (int mt = 0; mt < 4; ++mt)
        av[mt] = *(const short8*)(a1base + mt * (16 * 512) + aoff);
      #pragma unroll
      for (int mt = 0; mt < 4; ++mt)
        acc[mt] = __builtin_amdgcn_mfma_f32_16x16x32_bf16(av[mt], bv1, acc[mt], 0, 0, 0);
    }
    __syncthreads();   // all waves done reading feats

    // ---- (3) h1 writeback (bias+relu, bf16), swizzled, same buffer ----
    {
      const int n1 = wv * 16 + r16;
      const float bias1 = b1[n1];
      #pragma unroll
      for (int mt = 0; mt < 4; ++mt) {
        #pragma unroll
        for (int r = 0; r < 4; ++r) {
          int m = mt * 16 + q * 4 + r;            // C/D: row = 4*quad + reg
          float h = fmaxf(acc[mt][r] + bias1, 0.f);
          int ch = (n1 >> 3) ^ (m & 15);
          *(unsigned short*)(ldsb + m * 512 + (ch << 4) + ((n1 & 7) << 1)) = f2bf(h);
        }
      }
    }
    __syncthreads();   // h1 ready

    // ---- (4) GEMM2: wave owns 32 rows x 16 cols; K=256 ----
    const int mg2 = wv >> 3;        // 0..1: 32-row slab
    const int ng2 = wv & 7;         // 0..7: 16-col slab
    const unsigned short* const b2p = w2t + (ng2 * 16 + r16) * 256 + q * 8;
    floatx4 acc2[2];
    acc2[0] = (floatx4){0.f, 0.f, 0.f, 0.f};
    acc2[1] = (floatx4){0.f, 0.f, 0.f, 0.f};
    char* const a2base = ldsb + (mg2 * 32 + r16) * 512;
    #pragma unroll
    for (int kt = 0; kt < 8; ++kt) {
      const int aoff = (kt << 6) ^ ((q ^ r16) << 4);
      short8 bv2 = *(const short8*)(b2p + kt * 32);
      short8 av0 = *(const short8*)(a2base + aoff);
      short8 av1 = *(const short8*)(a2base + 16 * 512 + aoff);
      acc2[0] = __builtin_amdgcn_mfma_f32_16x16x32_bf16(av0, bv2, acc2[0], 0, 0, 0);
      acc2[1] = __builtin_amdgcn_mfma_f32_16x16x32_bf16(av1, bv2, acc2[1], 0, 0, 0);
    }

    // ---- (5) issue next-tile gather loads (latency hidden under phases 6-7) ----
    uintx4 ra[2], rb[2];
    #pragma unroll
    for (int s = 0; s < 2; ++s) {
      ra[s] = __builtin_nontemporal_load((const uintx4*)(xb + ((size_t)uvn[s].x << 8) + (c << 3)));
      rb[s] = __builtin_nontemporal_load((const uintx4*)(xb + ((size_t)uvn[s].y << 8) + (c << 3)));
    }

    // ---- (6) fused layer 3: out[g] += sum_n relu(h2)*W3  (out pre-init to b3) ----
    {
      const int n2 = ng2 * 16 + r16;
      const float b2v = b2[n2];
      const float w3v = w3[n2];
      #pragma unroll
      for (int mt = 0; mt < 2; ++mt) {
        #pragma unroll
        for (int r = 0; r < 4; ++r) {
          float h = fmaxf(acc2[mt][r] + b2v, 0.f);
          float pp = h * w3v;
          pp += __shfl_xor(pp, 1);
          pp += __shfl_xor(pp, 2);
          pp += __shfl_xor(pp, 4);
          pp += __shfl_xor(pp, 8);
          if (r16 == 0) {
            int g = t * MT + mg2 * 32 + mt * 16 + q * 4 + r;
            if (g < E) atomicAdd(out + g, pp);
          }
        }
      }
    }
    __syncthreads();   // all GEMM2 LDS reads done -> buffer reusable

    // ---- (7) convert + store next tile's feats into the same buffer ----
    #pragma unroll
    for (int s = 0; s < 2; ++s) {
      int m = mr0 + 32 * s;
      uintx4 pv;
      #pragma unroll
      for (int tt = 0; tt < 4; ++tt) pv[tt] = bf16mul2(ra[s][tt], rb[s][tt]);
      *(uintx4*)(ldsb + m * 512 + ((c ^ (m & 15)) << 4)) = pv;
    }
    __syncthreads();   // next feats ready
  }
}

extern "C" void kernel_launch(void* const* d_in, const int* in_sizes, int n_in,
                              void* d_out, int out_size, void* d_ws, size_t ws_size,
                              hipStream_t stream) {
  const float* x  = (const float*)d_in[0];
  const float* W1 = (const float*)d_in[1];
  const float* b1 = (const float*)d_in[2];
  const float* W2 = (const float*)d_in[3];
  const float* b2 = (const float*)d_in[4];
  const float* W3 = (const float*)d_in[5];
  const float* b3 = (const float*)d_in[6];
  // d_in[7] = edge_index (unused by the reference computation)
  const int*   ep = (const int*)d_in[8];
  float* out = (float*)d_out;

  const int NX = in_sizes[0];        // 100000*256 = 25,600,000
  const int E  = in_sizes[8] / 2;    // 1,000,000

  // workspace layout: xb (NX bf16) | w1t (256*256 bf16) | w2t (128*256 bf16)  ~49 MB
  unsigned short* xb  = (unsigned short*)d_ws;
  unsigned short* w1t = (unsigned short*)((char*)d_ws + (size_t)NX * 2);
  unsigned short* w2t = w1t + 256 * 256;

  init_out_kernel<<<(E + 255) / 256, 256, 0, stream>>>(out, b3, E);
  cast_x_kernel<<<(NX / 4 + 255) / 256, 256, 0, stream>>>(x, xb, NX / 4);
  prep_w_kernel<<<(256 * 256 + 128 * 256 + 255) / 256, 256, 0, stream>>>(W1, W2, w1t, w2t);
  mlp_kernel<<<NBLOCKS, NTHREADS, 0, stream>>>(xb, w1t, w2t, b1, b2, W3, ep, out, E);
}

// Round 7
// 878.404 us; speedup vs baseline: 1.0238x; 1.0238x over previous
//
#include <hip/hip_runtime.h>

// PairwiseMLPLinkPredictor on MI355X (gfx950)
// feats = bf16(x[u]) * bf16(x[v]);  h1 = relu(feats@W1+b1);  h2 = relu(h1@W2+b2);
// out = h2@W3 + b3.
//
// R6 = R5 with two fixes:
//  (1) NO nontemporal hints: NT gather at 32 waves/CU killed L2/L3 reuse of the
//      ~20x-repeated node rows (R5 FETCH 2.3 GB vs 0.48 GB; evict-first lines
//      died before reuse). Plain loads restore cache retention.
//  (2) layer-3 via LDS ss[] reduction + single coalesced store (R5's 8 global
//      atomics/pair caused 125-242 MB write-through; R3's LDS path was 3.9 MB).
// Keeps: persistent blocks, pipelined register-staged gather, single 32 KB LDS
// buffer, lean regs (VGPR~32 -> 8 waves/SIMD, 2x16-wave blocks/CU).

typedef __attribute__((ext_vector_type(8))) short short8;   // 8 bf16 = 4 VGPRs
typedef __attribute__((ext_vector_type(4))) float floatx4;  // MFMA C/D frag
typedef __attribute__((ext_vector_type(4))) unsigned uintx4;
typedef __attribute__((ext_vector_type(2))) int intx2;

#define MT 64         // pairs per tile
#define NTHREADS 1024 // 16 waves
#define NBLOCKS 512   // 2 blocks/CU resident

__device__ __forceinline__ unsigned short f2bf(float f) {
  union { float f; unsigned u; } a; a.f = f;
  unsigned r = a.u + 0x7FFFu + ((a.u >> 16) & 1u);   // RNE
  return (unsigned short)(r >> 16);
}

// packed bf16 x2 multiply via f32 (unpack, mul, RNE repack)
__device__ __forceinline__ unsigned bf16mul2(unsigned ua, unsigned ub) {
  float lo = __uint_as_float(ua << 16)          * __uint_as_float(ub << 16);
  float hi = __uint_as_float(ua & 0xFFFF0000u) * __uint_as_float(ub & 0xFFFF0000u);
  return (unsigned)f2bf(lo) | ((unsigned)f2bf(hi) << 16);
}

// ---------- prologue: x -> bf16 table ----------
__global__ void cast_x_kernel(const float* __restrict__ x, unsigned short* __restrict__ xb, int n4) {
  int i = blockIdx.x * blockDim.x + threadIdx.x;
  if (i >= n4) return;
  float4 v = ((const float4*)x)[i];
  ushort4 o;
  o.x = f2bf(v.x); o.y = f2bf(v.y); o.z = f2bf(v.z); o.w = f2bf(v.w);
  ((ushort4*)xb)[i] = o;
}

// ---------- prologue: W1 [256,256] / W2 [256,128] -> bf16, transposed to [n][k] ----------
__global__ void prep_w_kernel(const float* __restrict__ W1, const float* __restrict__ W2,
                              unsigned short* __restrict__ w1t, unsigned short* __restrict__ w2t) {
  int i = blockIdx.x * blockDim.x + threadIdx.x;
  if (i < 256 * 256) {
    int k = i >> 8, n = i & 255;
    w1t[n * 256 + k] = f2bf(W1[k * 256 + n]);
  } else {
    int j = i - 256 * 256;
    if (j < 128 * 256) {
      int k = j >> 7, n = j & 127;
      w2t[n * 256 + k] = f2bf(W2[k * 128 + n]);
    }
  }
}

// ---------- fused pairwise MLP, persistent + pipelined, single LDS buffer ----------
__global__ __launch_bounds__(NTHREADS, 8) void mlp_kernel(
    const unsigned short* __restrict__ xb,
    const unsigned short* __restrict__ w1t,
    const unsigned short* __restrict__ w2t,
    const float* __restrict__ b1,
    const float* __restrict__ b2,
    const float* __restrict__ w3,
    const float* __restrict__ b3,
    const int* __restrict__ ep,
    float* __restrict__ out,
    int E)
{
  // 64 rows x 256 bf16 = 32768 B. 16B chunks XOR-swizzled by (row & 15):
  // conflict-free stride-512 ds_read_b128 without padding.
  __shared__ __align__(16) unsigned short buf[MT * 256];
  __shared__ float ss[MT];
  char* const ldsb = (char*)buf;

  const int tid  = threadIdx.x;
  const int wv   = tid >> 6;      // 0..15
  const int lane = tid & 63;
  const int q    = lane >> 4;     // quad 0..3
  const int r16  = lane & 15;
  const int c    = tid & 31;      // 16B chunk within 512B row (staging)
  const int mr0  = tid >> 5;      // staging rows mr0, mr0+32

  const int ntiles = (E + MT - 1) / MT;
  const float b3v = b3[0];

  if (tid < MT) ss[tid] = 0.f;

  // ---- prologue: stage tile t0 ----
  {
    int t0 = blockIdx.x;
    #pragma unroll
    for (int s = 0; s < 2; ++s) {
      int m = mr0 + 32 * s;
      int g = t0 * MT + m; if (g >= E) g = E - 1;
      intx2 uv = *(const intx2*)(ep + 2 * (size_t)g);
      uintx4 a = *(const uintx4*)(xb + ((size_t)uv.x << 8) + (c << 3));
      uintx4 b = *(const uintx4*)(xb + ((size_t)uv.y << 8) + (c << 3));
      uintx4 pv;
      #pragma unroll
      for (int tt = 0; tt < 4; ++tt) pv[tt] = bf16mul2(a[tt], b[tt]);
      *(uintx4*)(ldsb + m * 512 + ((c ^ (m & 15)) << 4)) = pv;
    }
  }
  __syncthreads();

  for (int t = blockIdx.x; t < ntiles; t += NBLOCKS) {
    const int tn = (t + NBLOCKS < ntiles) ? (t + NBLOCKS) : t;

    // ---- (1) prefetch ep indices for next tile ----
    intx2 uvn[2];
    #pragma unroll
    for (int s = 0; s < 2; ++s) {
      int g = tn * MT + mr0 + 32 * s; if (g >= E) g = E - 1;
      uvn[s] = *(const intx2*)(ep + 2 * (size_t)g);
    }

    // ---- (2) GEMM1: wave owns 64 rows x 16 cols (n = wv*16 + r16) ----
    const unsigned short* const b1p = w1t + (wv * 16 + r16) * 256 + q * 8;
    floatx4 acc[4];
    #pragma unroll
    for (int i = 0; i < 4; ++i) acc[i] = (floatx4){0.f, 0.f, 0.f, 0.f};

    char* const a1base = ldsb + r16 * 512;
    #pragma unroll
    for (int kt = 0; kt < 8; ++kt) {
      const int aoff = (kt << 6) ^ ((q ^ r16) << 4);
      short8 bv1 = *(const short8*)(b1p + kt * 32);
      short8 av[4];
      #pragma unroll
      for (int mt = 0; mt < 4; ++mt)
        av[mt] = *(const short8*)(a1base + mt * (16 * 512) + aoff);
      #pragma unroll
      for (int mt = 0; mt < 4; ++mt)
        acc[mt] = __builtin_amdgcn_mfma_f32_16x16x32_bf16(av[mt], bv1, acc[mt], 0, 0, 0);
    }
    __syncthreads();   // all waves done reading feats

    // ---- (3) h1 writeback (bias+relu, bf16), swizzled, same buffer ----
    {
      const int n1 = wv * 16 + r16;
      const float bias1 = b1[n1];
      #pragma unroll
      for (int mt = 0; mt < 4; ++mt) {
        #pragma unroll
        for (int r = 0; r < 4; ++r) {
          int m = mt * 16 + q * 4 + r;            // C/D: row = 4*quad + reg
          float h = fmaxf(acc[mt][r] + bias1, 0.f);
          int ch = (n1 >> 3) ^ (m & 15);
          *(unsigned short*)(ldsb + m * 512 + (ch << 4) + ((n1 & 7) << 1)) = f2bf(h);
        }
      }
    }
    __syncthreads();   // h1 ready

    // ---- (4) GEMM2: wave owns 32 rows x 16 cols; K=256 ----
    const int mg2 = wv >> 3;        // 0..1: 32-row slab
    const int ng2 = wv & 7;         // 0..7: 16-col slab
    const unsigned short* const b2p = w2t + (ng2 * 16 + r16) * 256 + q * 8;
    floatx4 acc2[2];
    acc2[0] = (floatx4){0.f, 0.f, 0.f, 0.f};
    acc2[1] = (floatx4){0.f, 0.f, 0.f, 0.f};
    char* const a2base = ldsb + (mg2 * 32 + r16) * 512;
    #pragma unroll
    for (int kt = 0; kt < 8; ++kt) {
      const int aoff = (kt << 6) ^ ((q ^ r16) << 4);
      short8 bv2 = *(const short8*)(b2p + kt * 32);
      short8 av0 = *(const short8*)(a2base + aoff);
      short8 av1 = *(const short8*)(a2base + 16 * 512 + aoff);
      acc2[0] = __builtin_amdgcn_mfma_f32_16x16x32_bf16(av0, bv2, acc2[0], 0, 0, 0);
      acc2[1] = __builtin_amdgcn_mfma_f32_16x16x32_bf16(av1, bv2, acc2[1], 0, 0, 0);
    }

    // ---- (5) issue next-tile gather loads (latency hidden under phase 6) ----
    uintx4 ra[2], rb[2];
    #pragma unroll
    for (int s = 0; s < 2; ++s) {
      ra[s] = *(const uintx4*)(xb + ((size_t)uvn[s].x << 8) + (c << 3));
      rb[s] = *(const uintx4*)(xb + ((size_t)uvn[s].y << 8) + (c << 3));
    }

    // ---- (6) fused layer 3 partials -> LDS ss[] ----
    {
      const int n2 = ng2 * 16 + r16;
      const float b2v = b2[n2];
      const float w3v = w3[n2];
      #pragma unroll
      for (int mt = 0; mt < 2; ++mt) {
        #pragma unroll
        for (int r = 0; r < 4; ++r) {
          float h = fmaxf(acc2[mt][r] + b2v, 0.f);
          float pp = h * w3v;
          pp += __shfl_xor(pp, 1);
          pp += __shfl_xor(pp, 2);
          pp += __shfl_xor(pp, 4);
          pp += __shfl_xor(pp, 8);
          if (r16 == 0)
            atomicAdd(&ss[mg2 * 32 + mt * 16 + q * 4 + r], pp);
        }
      }
    }
    __syncthreads();   // ss complete; all GEMM2 LDS reads done -> buffer reusable

    // ---- (7) store scores; re-init ss; stage next tile's feats ----
    if (tid < MT) {
      int g = t * MT + tid;
      if (g < E) out[g] = ss[tid] + b3v;
      ss[tid] = 0.f;
    }
    #pragma unroll
    for (int s = 0; s < 2; ++s) {
      int m = mr0 + 32 * s;
      uintx4 pv;
      #pragma unroll
      for (int tt = 0; tt < 4; ++tt) pv[tt] = bf16mul2(ra[s][tt], rb[s][tt]);
      *(uintx4*)(ldsb + m * 512 + ((c ^ (m & 15)) << 4)) = pv;
    }
    __syncthreads();   // next feats + zeroed ss ready
  }
}

extern "C" void kernel_launch(void* const* d_in, const int* in_sizes, int n_in,
                              void* d_out, int out_size, void* d_ws, size_t ws_size,
                              hipStream_t stream) {
  const float* x  = (const float*)d_in[0];
  const float* W1 = (const float*)d_in[1];
  const float* b1 = (const float*)d_in[2];
  const float* W2 = (const float*)d_in[3];
  const float* b2 = (const float*)d_in[4];
  const float* W3 = (const float*)d_in[5];
  const float* b3 = (const float*)d_in[6];
  // d_in[7] = edge_index (unused by the reference computation)
  const int*   ep = (const int*)d_in[8];
  float* out = (float*)d_out;

  const int NX = in_sizes[0];        // 100000*256 = 25,600,000
  const int E  = in_sizes[8] / 2;    // 1,000,000

  // workspace layout: xb (NX bf16) | w1t (256*256 bf16) | w2t (128*256 bf16)  ~49 MB
  unsigned short* xb  = (unsigned short*)d_ws;
  unsigned short* w1t = (unsigned short*)((char*)d_ws + (size_t)NX * 2);
  unsigned short* w2t = w1t + 256 * 256;

  cast_x_kernel<<<(NX / 4 + 255) / 256, 256, 0, stream>>>(x, xb, NX / 4);
  prep_w_kernel<<<(256 * 256 + 128 * 256 + 255) / 256, 256, 0, stream>>>(W1, W2, w1t, w2t);
  mlp_kernel<<<NBLOCKS, NTHREADS, 0, stream>>>(xb, w1t, w2t, b1, b2, W3, b3, ep, out, E);
}

// Round 8
// 849.573 us; speedup vs baseline: 1.0586x; 1.0339x over previous
//
#include <hip/hip_runtime.h>

// PairwiseMLPLinkPredictor on MI355X (gfx950)
// feats = bf16(x[u]) * bf16(x[v]);  h1 = relu(feats@W1+b1);  h2 = relu(h1@W2+b2);
// out = h2@W3 + b3.
//
// R7: R4b (388 us, best) restructured to cut the LDS-pipe load:
//  - wave grid M2xN8 for GEMM1 (wave = 32 rows x 32 cols): A-fragment LDS
//    amplification 16x -> 8x (R4b: every wave read all 64 rows).
//  - weights stay BATCH-PRELOADED off the K-loop critical path (the R4b-vs-
//    R5/R6 lesson: per-kt weight loads + gather EA congestion = 2x slowdown).
//    GEMM1 B in two 32-reg K-half batches; GEMM2 B one 32-reg batch.
//  - separate 32 KB h1 buffer -> h1 writeback doesn't collide with feat reads
//    -> 2 barriers/tile. LDS = 2x32 (feats dbuf) + 32 (h1) + ss = 96.5 KB, 1 block/CU.
//  - keep: pipelined register-staged gather, LDS-ss layer-3 (low WRITE), no NT.

typedef __attribute__((ext_vector_type(8))) short short8;   // 8 bf16 = 4 VGPRs
typedef __attribute__((ext_vector_type(4))) float floatx4;  // MFMA C/D frag
typedef __attribute__((ext_vector_type(4))) unsigned uintx4;
typedef __attribute__((ext_vector_type(2))) int intx2;

#define MT 64         // pairs per tile
#define NTHREADS 1024 // 16 waves
#define NBLOCKS 256   // persistent, 1 block/CU (96 KB LDS)

__device__ __forceinline__ unsigned short f2bf(float f) {
  union { float f; unsigned u; } a; a.f = f;
  unsigned r = a.u + 0x7FFFu + ((a.u >> 16) & 1u);   // RNE
  return (unsigned short)(r >> 16);
}

// packed bf16 x2 multiply via f32 (unpack, mul, RNE repack)
__device__ __forceinline__ unsigned bf16mul2(unsigned ua, unsigned ub) {
  float lo = __uint_as_float(ua << 16)          * __uint_as_float(ub << 16);
  float hi = __uint_as_float(ua & 0xFFFF0000u) * __uint_as_float(ub & 0xFFFF0000u);
  return (unsigned)f2bf(lo) | ((unsigned)f2bf(hi) << 16);
}

// ---------- prologue: x -> bf16 table ----------
__global__ void cast_x_kernel(const float* __restrict__ x, unsigned short* __restrict__ xb, int n4) {
  int i = blockIdx.x * blockDim.x + threadIdx.x;
  if (i >= n4) return;
  float4 v = ((const float4*)x)[i];
  ushort4 o;
  o.x = f2bf(v.x); o.y = f2bf(v.y); o.z = f2bf(v.z); o.w = f2bf(v.w);
  ((ushort4*)xb)[i] = o;
}

// ---------- prologue: W1 [256,256] / W2 [256,128] -> bf16, transposed to [n][k] ----------
__global__ void prep_w_kernel(const float* __restrict__ W1, const float* __restrict__ W2,
                              unsigned short* __restrict__ w1t, unsigned short* __restrict__ w2t) {
  int i = blockIdx.x * blockDim.x + threadIdx.x;
  if (i < 256 * 256) {
    int k = i >> 8, n = i & 255;
    w1t[n * 256 + k] = f2bf(W1[k * 256 + n]);
  } else {
    int j = i - 256 * 256;
    if (j < 128 * 256) {
      int k = j >> 7, n = j & 127;
      w2t[n * 256 + k] = f2bf(W2[k * 128 + n]);
    }
  }
}

// ---------- fused pairwise MLP, persistent + pipelined ----------
__global__ __launch_bounds__(NTHREADS, 4) void mlp_kernel(
    const unsigned short* __restrict__ xb,
    const unsigned short* __restrict__ w1t,
    const unsigned short* __restrict__ w2t,
    const float* __restrict__ b1,
    const float* __restrict__ b2,
    const float* __restrict__ w3,
    const float* __restrict__ b3,
    const int* __restrict__ ep,
    float* __restrict__ out,
    int E)
{
  // Row stride 512 B; 16B chunks XOR-swizzled by (row & 15): conflict-free
  // stride-512 ds_read_b128 without padding. fbuf: feats double buffer;
  // h1buf: disjoint so h1 writeback needs no barrier against feat reads.
  __shared__ __align__(16) unsigned short fbuf[2][MT * 256];  // 2 x 32 KB
  __shared__ __align__(16) unsigned short h1buf[MT * 256];    // 32 KB
  __shared__ float ss[MT];

  const int tid  = threadIdx.x;
  const int wv   = tid >> 6;      // 0..15
  const int lane = tid & 63;
  const int q    = lane >> 4;     // quad 0..3
  const int r16  = lane & 15;
  const int c    = tid & 31;      // 16B chunk within 512B row (staging)
  const int mr0  = tid >> 5;      // staging rows mr0, mr0+32
  const int mg   = wv >> 3;       // 0..1: 32-row slab (both GEMMs)
  const int ng   = wv & 7;        // 0..7: 32-col slab (GEMM1) / 16-col (GEMM2)
  const int swz16 = (q ^ r16) << 4;
  char* const h1b = (char*)h1buf;

  const int ntiles = (E + MT - 1) / MT;
  const float b3v = b3[0];

  if (tid < MT) ss[tid] = 0.f;

  // ---- prologue: stage tile t0 into fbuf[0] ----
  {
    int t0 = blockIdx.x;
    #pragma unroll
    for (int s = 0; s < 2; ++s) {
      int m = mr0 + 32 * s;
      int g = t0 * MT + m; if (g >= E) g = E - 1;
      intx2 uv = *(const intx2*)(ep + 2 * (size_t)g);
      uintx4 a = *(const uintx4*)(xb + ((size_t)uv.x << 8) + (c << 3));
      uintx4 b = *(const uintx4*)(xb + ((size_t)uv.y << 8) + (c << 3));
      uintx4 pv;
      #pragma unroll
      for (int tt = 0; tt < 4; ++tt) pv[tt] = bf16mul2(a[tt], b[tt]);
      *(uintx4*)((char*)fbuf[0] + m * 512 + ((c ^ (m & 15)) << 4)) = pv;
    }
  }
  __syncthreads();

  int p = 0;
  for (int t = blockIdx.x; t < ntiles; t += NBLOCKS) {
    char* const bufp = (char*)fbuf[p];
    char* const bufn = (char*)fbuf[p ^ 1];
    const int tn = (t + NBLOCKS < ntiles) ? (t + NBLOCKS) : t;

    // ---- (1) prefetch ep indices for next tile ----
    intx2 uvn[2];
    #pragma unroll
    for (int s = 0; s < 2; ++s) {
      int g = tn * MT + mr0 + 32 * s; if (g >= E) g = E - 1;
      uvn[s] = *(const intx2*)(ep + 2 * (size_t)g);
    }

    // ---- (2) GEMM1: wave owns 32 rows x 32 cols; B preloaded per K-half ----
    const unsigned short* const b1p0 = w1t + (ng * 32 + r16) * 256 + q * 8;       // nt=0
    const unsigned short* const b1p1 = b1p0 + 16 * 256;                            // nt=1
    floatx4 acc[2][2];
    #pragma unroll
    for (int i = 0; i < 2; ++i)
      #pragma unroll
      for (int j = 0; j < 2; ++j)
        acc[i][j] = (floatx4){0.f, 0.f, 0.f, 0.f};

    char* const a1base = bufp + (mg * 32 + r16) * 512;
    #pragma unroll
    for (int half = 0; half < 2; ++half) {
      short8 bv[2][4];
      #pragma unroll
      for (int kk = 0; kk < 4; ++kk) {
        bv[0][kk] = *(const short8*)(b1p0 + (half * 4 + kk) * 32);
        bv[1][kk] = *(const short8*)(b1p1 + (half * 4 + kk) * 32);
      }
      #pragma unroll
      for (int kk = 0; kk < 4; ++kk) {
        const int kt = half * 4 + kk;
        const int aoff = (kt << 6) ^ swz16;
        short8 av0 = *(const short8*)(a1base + aoff);
        short8 av1 = *(const short8*)(a1base + 16 * 512 + aoff);
        acc[0][0] = __builtin_amdgcn_mfma_f32_16x16x32_bf16(av0, bv[0][kk], acc[0][0], 0, 0, 0);
        acc[0][1] = __builtin_amdgcn_mfma_f32_16x16x32_bf16(av0, bv[1][kk], acc[0][1], 0, 0, 0);
        acc[1][0] = __builtin_amdgcn_mfma_f32_16x16x32_bf16(av1, bv[0][kk], acc[1][0], 0, 0, 0);
        acc[1][1] = __builtin_amdgcn_mfma_f32_16x16x32_bf16(av1, bv[1][kk], acc[1][1], 0, 0, 0);
      }
    }

    // ---- (3) h1 writeback (bias+relu, bf16) -> h1buf (disjoint: no barrier) ----
    {
      #pragma unroll
      for (int nt = 0; nt < 2; ++nt) {
        const int n1 = ng * 32 + nt * 16 + r16;
        const float bias1 = b1[n1];
        #pragma unroll
        for (int mt = 0; mt < 2; ++mt) {
          #pragma unroll
          for (int r = 0; r < 4; ++r) {
            int mlo = q * 4 + r;                  // C/D: row = 4*quad + reg
            int m = mg * 32 + mt * 16 + mlo;
            float h = fmaxf(acc[mt][nt][r] + bias1, 0.f);
            int ch = (n1 >> 3) ^ mlo;
            *(unsigned short*)(h1b + m * 512 + (ch << 4) + ((n1 & 7) << 1)) = f2bf(h);
          }
        }
      }
    }
    __syncthreads();   // B1: h1 complete (also: all feat reads from bufp done)

    // ---- (4) GEMM2 B preload, then issue next-tile gather loads ----
    const unsigned short* const b2p = w2t + (ng * 16 + r16) * 256 + q * 8;
    short8 bv2[8];
    #pragma unroll
    for (int kt = 0; kt < 8; ++kt) bv2[kt] = *(const short8*)(b2p + kt * 32);

    uintx4 ra[2], rb[2];
    #pragma unroll
    for (int s = 0; s < 2; ++s) {
      ra[s] = *(const uintx4*)(xb + ((size_t)uvn[s].x << 8) + (c << 3));
      rb[s] = *(const uintx4*)(xb + ((size_t)uvn[s].y << 8) + (c << 3));
    }

    // ---- (5) GEMM2: wave owns 32 rows x 16 cols; K=256 ----
    floatx4 acc2[2];
    acc2[0] = (floatx4){0.f, 0.f, 0.f, 0.f};
    acc2[1] = (floatx4){0.f, 0.f, 0.f, 0.f};
    char* const a2base = h1b + (mg * 32 + r16) * 512;
    #pragma unroll
    for (int kt = 0; kt < 8; ++kt) {
      const int aoff = (kt << 6) ^ swz16;
      short8 av0 = *(const short8*)(a2base + aoff);
      short8 av1 = *(const short8*)(a2base + 16 * 512 + aoff);
      acc2[0] = __builtin_amdgcn_mfma_f32_16x16x32_bf16(av0, bv2[kt], acc2[0], 0, 0, 0);
      acc2[1] = __builtin_amdgcn_mfma_f32_16x16x32_bf16(av1, bv2[kt], acc2[1], 0, 0, 0);
    }

    // ---- (6) fused layer 3 partials -> LDS ss[] ----
    {
      const int n2 = ng * 16 + r16;
      const float b2v = b2[n2];
      const float w3v = w3[n2];
      #pragma unroll
      for (int mt = 0; mt < 2; ++mt) {
        #pragma unroll
        for (int r = 0; r < 4; ++r) {
          float h = fmaxf(acc2[mt][r] + b2v, 0.f);
          float pp = h * w3v;
          pp += __shfl_xor(pp, 1);
          pp += __shfl_xor(pp, 2);
          pp += __shfl_xor(pp, 4);
          pp += __shfl_xor(pp, 8);
          if (r16 == 0)
            atomicAdd(&ss[mg * 32 + mt * 16 + q * 4 + r], pp);
        }
      }
    }

    // ---- (7) stage next tile's feats into bufn (disjoint from bufp/h1b) ----
    #pragma unroll
    for (int s = 0; s < 2; ++s) {
      int m = mr0 + 32 * s;
      uintx4 pv;
      #pragma unroll
      for (int tt = 0; tt < 4; ++tt) pv[tt] = bf16mul2(ra[s][tt], rb[s][tt]);
      *(uintx4*)(bufn + m * 512 + ((c ^ (m & 15)) << 4)) = pv;
    }
    __syncthreads();   // B2: ss complete, bufn staged, h1buf reads done

    // ---- (8) store scores; re-init ss ----
    if (tid < MT) {
      int g = t * MT + tid;
      if (g < E) out[g] = ss[tid] + b3v;
      ss[tid] = 0.f;
    }
    p ^= 1;
  }
}

extern "C" void kernel_launch(void* const* d_in, const int* in_sizes, int n_in,
                              void* d_out, int out_size, void* d_ws, size_t ws_size,
                              hipStream_t stream) {
  const float* x  = (const float*)d_in[0];
  const float* W1 = (const float*)d_in[1];
  const float* b1 = (const float*)d_in[2];
  const float* W2 = (const float*)d_in[3];
  const float* b2 = (const float*)d_in[4];
  const float* W3 = (const float*)d_in[5];
  const float* b3 = (const float*)d_in[6];
  // d_in[7] = edge_index (unused by the reference computation)
  const int*   ep = (const int*)d_in[8];
  float* out = (float*)d_out;

  const int NX = in_sizes[0];        // 100000*256 = 25,600,000
  const int E  = in_sizes[8] / 2;    // 1,000,000

  // workspace layout: xb (NX bf16) | w1t (256*256 bf16) | w2t (128*256 bf16)  ~49 MB
  unsigned short* xb  = (unsigned short*)d_ws;
  unsigned short* w1t = (unsigned short*)((char*)d_ws + (size_t)NX * 2);
  unsigned short* w2t = w1t + 256 * 256;

  cast_x_kernel<<<(NX / 4 + 255) / 256, 256, 0, stream>>>(x, xb, NX / 4);
  prep_w_kernel<<<(256 * 256 + 128 * 256 + 255) / 256, 256, 0, stream>>>(W1, W2, w1t, w2t);
  mlp_kernel<<<NBLOCKS, NTHREADS, 0, stream>>>(xb, w1t, w2t, b1, b2, W3, b3, ep, out, E);
}